// Round 1
// baseline (359.265 us; speedup 1.0000x reference)
//
#include <hip/hip_runtime.h>
#include <math.h>

#define M_ROWS 16384   // B*S
#define E_DIM 768
#define FFN_DIM 3072
#define NQ 8
#define LDA 72         // 64 + 8 pad (elements); row stride 144B rotates banks by 4/row

typedef __bf16 bf16x8 __attribute__((ext_vector_type(8)));
typedef float f32x4 __attribute__((ext_vector_type(4)));
typedef unsigned short ushortx8 __attribute__((ext_vector_type(8)));
typedef unsigned short ushortx4 __attribute__((ext_vector_type(4)));
typedef unsigned short ushort;

static __device__ __forceinline__ ushort f2bf(float f) {
    unsigned u = __float_as_uint(f);
    unsigned r = (u + 0x7FFFu + ((u >> 16) & 1u)) >> 16;
    return (ushort)r;
}

static __device__ __forceinline__ bf16x8 as_bf16x8(ushortx8 v) {
    union { ushortx8 u; bf16x8 b; } x; x.u = v; return x.b;
}

// ---------------------------------------------------------------------------
// Kernel 1: A1[m,e] = bf16( cos(x[m,e] + rx[e & 63]) )
// (e%64 == global_idx%64 because 768 % 64 == 0)
// ---------------------------------------------------------------------------
__global__ __launch_bounds__(256) void k_prep_a1(const float* __restrict__ x,
                                                 const float* __restrict__ rx,
                                                 ushort* __restrict__ a1) {
    long idx = ((long)blockIdx.x * 256 + threadIdx.x) * 4;
    float4 v = *(const float4*)(x + idx);
    int r = (int)(idx & 63);
    ushortx4 o;
    o[0] = f2bf(__cosf(v.x + rx[r + 0]));
    o[1] = f2bf(__cosf(v.y + rx[r + 1]));
    o[2] = f2bf(__cosf(v.z + rx[r + 2]));
    o[3] = f2bf(__cosf(v.w + rx[r + 3]));
    *(ushortx4*)(a1 + idx) = o;
}

// ---------------------------------------------------------------------------
// Kernel 2: LDS-tiled transpose fp32 (R x C) -> bf16 (C x R)
// ---------------------------------------------------------------------------
__global__ __launch_bounds__(256) void k_transpose_bf(const float* __restrict__ in,
                                                      ushort* __restrict__ out,
                                                      int R, int C) {
    __shared__ float tile[32][33];
    int c0 = blockIdx.x * 32, r0 = blockIdx.y * 32;
    int tx = threadIdx.x & 31, ty = threadIdx.x >> 5;  // ty in 0..7
#pragma unroll
    for (int i = 0; i < 32; i += 8) {
        tile[ty + i][tx] = in[(long)(r0 + ty + i) * C + c0 + tx];
    }
    __syncthreads();
#pragma unroll
    for (int i = 0; i < 32; i += 8) {
        out[(long)(c0 + ty + i) * R + r0 + tx] = f2bf(tile[tx][ty + i]);
    }
}

// ---------------------------------------------------------------------------
// Kernel 3: bf16 MFMA GEMM, C[M,N] = A[M,K] * Bt[N,K]^T + bias[N], fp32 out.
// 128x128 tile, 4 waves (2x2), each wave 64x64 = 4x4 of 16x16x32 MFMA.
// ---------------------------------------------------------------------------
__global__ __launch_bounds__(256, 2)
void k_gemm_bt(const ushort* __restrict__ A, const ushort* __restrict__ Bt,
               const float* __restrict__ bias, float* __restrict__ C,
               int M, int N, int K) {
    __shared__ ushort lsA[128 * LDA];
    __shared__ ushort lsB[128 * LDA];
    const int tid = threadIdx.x;
    const int lane = tid & 63;
    const int wave = tid >> 6;
    const int wm = wave & 1, wn = wave >> 1;
    const long m0 = (long)blockIdx.x * 128;
    const long n0 = (long)blockIdx.y * 128;

    // staging: thread -> (row = tid>>3, 8-elem chunk col = (tid&7)*8), 4 rows apart by 32
    const int srow = tid >> 3;
    const int scol = (tid & 7) * 8;
    const ushort* gA = A + (m0 + srow) * (long)K + scol;
    const ushort* gB = Bt + (n0 + srow) * (long)K + scol;

    f32x4 acc[4][4] = {};

    const int fr = lane & 15;        // fragment m/n within 16
    const int fk = (lane >> 4) * 8;  // fragment k offset

    for (int kt = 0; kt < K; kt += 64) {
        ushortx8 av[4], bv[4];
#pragma unroll
        for (int i = 0; i < 4; ++i) {
            av[i] = *(const ushortx8*)(gA + kt + (long)(32 * i) * K);
            bv[i] = *(const ushortx8*)(gB + kt + (long)(32 * i) * K);
        }
        if (kt) __syncthreads();
#pragma unroll
        for (int i = 0; i < 4; ++i) {
            *(ushortx8*)&lsA[(srow + 32 * i) * LDA + scol] = av[i];
            *(ushortx8*)&lsB[(srow + 32 * i) * LDA + scol] = bv[i];
        }
        __syncthreads();
#pragma unroll
        for (int kk = 0; kk < 64; kk += 32) {
            bf16x8 af[4], bfr[4];
#pragma unroll
            for (int t = 0; t < 4; ++t) {
                af[t]  = as_bf16x8(*(const ushortx8*)&lsA[(wm * 64 + t * 16 + fr) * LDA + kk + fk]);
                bfr[t] = as_bf16x8(*(const ushortx8*)&lsB[(wn * 64 + t * 16 + fr) * LDA + kk + fk]);
            }
#pragma unroll
            for (int tm = 0; tm < 4; ++tm)
#pragma unroll
                for (int tn = 0; tn < 4; ++tn)
                    acc[tm][tn] = __builtin_amdgcn_mfma_f32_16x16x32_bf16(af[tm], bfr[tn], acc[tm][tn], 0, 0, 0);
        }
    }

    // epilogue: C/D layout col = lane&15, row = (lane>>4)*4 + j  [m89/m91 verified]
    const int cr = (lane >> 4) * 4;
    const int cc = lane & 15;
#pragma unroll
    for (int tm = 0; tm < 4; ++tm) {
#pragma unroll
        for (int tn = 0; tn < 4; ++tn) {
            long col = n0 + wn * 64 + tn * 16 + cc;
            float bb = bias[col];
#pragma unroll
            for (int j = 0; j < 4; ++j) {
                long row = m0 + wm * 64 + tm * 16 + cr + j;
                C[row * N + col] = acc[tm][tn][j] + bb;
            }
        }
    }
}

// ---------------------------------------------------------------------------
// Kernel 4: fused residual + LayerNorm (+ optional q = cos(x1[:, :8])*cos(ry))
// one block per row of 768; 256 threads x 3 elements
// ---------------------------------------------------------------------------
__global__ __launch_bounds__(256) void k_ln(const float* __restrict__ x,
                                            const float* __restrict__ y,
                                            const float* __restrict__ g,
                                            const float* __restrict__ b,
                                            float* __restrict__ out,
                                            float* __restrict__ qout,
                                            const float* __restrict__ ry,
                                            int withq) {
    __shared__ float red_s[4], red_ss[4], stats[2];
    const long row = blockIdx.x;
    const int tid = threadIdx.x;
    const float* xr = x + row * E_DIM;
    const float* yr = y + row * E_DIM;
    float v[3];
    float s = 0.f, ss = 0.f;
#pragma unroll
    for (int i = 0; i < 3; ++i) {
        v[i] = xr[tid + 256 * i] + yr[tid + 256 * i];
        s += v[i];
        ss += v[i] * v[i];
    }
#pragma unroll
    for (int o = 32; o; o >>= 1) {
        s += __shfl_down(s, o);
        ss += __shfl_down(ss, o);
    }
    const int wv = tid >> 6;
    if ((tid & 63) == 0) { red_s[wv] = s; red_ss[wv] = ss; }
    __syncthreads();
    if (tid == 0) {
        float S = red_s[0] + red_s[1] + red_s[2] + red_s[3];
        float SS = red_ss[0] + red_ss[1] + red_ss[2] + red_ss[3];
        float mu = S * (1.f / E_DIM);
        float var = SS * (1.f / E_DIM) - mu * mu;
        stats[0] = mu;
        stats[1] = rsqrtf(var + 1e-5f);
    }
    __syncthreads();
    float mu = stats[0], rstd = stats[1];
#pragma unroll
    for (int i = 0; i < 3; ++i) {
        int c = tid + 256 * i;
        float xn = (v[i] - mu) * rstd * g[c] + b[c];
        out[row * E_DIM + c] = xn;
        if (withq && i == 0 && tid < NQ) {
            qout[row * NQ + tid] = __cosf(xn) * __cosf(ry[tid]);
        }
    }
}

// ---------------------------------------------------------------------------
// Kernel 5: h[m,n] = relu(b1[n] + sum_{j<8} q[m,j]*W1[j,n]), bf16 out.
// Block: 32 rows x all 3072 cols (12 per thread).
// ---------------------------------------------------------------------------
__global__ __launch_bounds__(256) void k_ffn1(const float* __restrict__ q,
                                              const float* __restrict__ W1,
                                              const float* __restrict__ b1,
                                              ushort* __restrict__ h) {
    __shared__ float qs[32][NQ];
    const int r0 = blockIdx.x * 32;
    const int tid = threadIdx.x;
    qs[tid >> 3][tid & 7] = q[(long)r0 * NQ + tid];
    __syncthreads();
#pragma unroll 4
    for (int nb = 0; nb < 12; ++nb) {
        int n = nb * 256 + tid;
        float w[NQ];
#pragma unroll
        for (int j = 0; j < NQ; ++j) w[j] = W1[j * FFN_DIM + n];
        float bb = b1[n];
#pragma unroll
        for (int r = 0; r < 32; ++r) {
            float a = bb;
#pragma unroll
            for (int j = 0; j < NQ; ++j) a += qs[r][j] * w[j];
            a = a > 0.f ? a : 0.f;
            h[(long)(r0 + r) * FFN_DIM + n] = f2bf(a);
        }
    }
}

// ---------------------------------------------------------------------------

extern "C" void kernel_launch(void* const* d_in, const int* in_sizes, int n_in,
                              void* d_out, int out_size, void* d_ws, size_t ws_size,
                              hipStream_t stream) {
    const float* x   = (const float*)d_in[0];
    const float* rx  = (const float*)d_in[1];
    const float* ry  = (const float*)d_in[2];
    const float* Wc  = (const float*)d_in[3];
    const float* bc  = (const float*)d_in[4];
    const float* W1  = (const float*)d_in[5];
    const float* b1  = (const float*)d_in[6];
    const float* W2  = (const float*)d_in[7];
    const float* b2  = (const float*)d_in[8];
    const float* g1  = (const float*)d_in[9];
    const float* be1 = (const float*)d_in[10];
    const float* g2  = (const float*)d_in[11];
    const float* be2 = (const float*)d_in[12];
    float* out = (float*)d_out;

    char* ws = (char*)d_ws;
    ushort* a1   = (ushort*)ws;                 ws += (size_t)M_ROWS * E_DIM * 2;     // 25.2 MB
    ushort* wcT  = (ushort*)ws;                 ws += (size_t)E_DIM * E_DIM * 2;      // 1.2 MB
    float*  attn = (float*)ws;                  ws += (size_t)M_ROWS * E_DIM * 4;     // 50.3 MB (reused as ffn_out)
    float*  x1   = (float*)ws;                  ws += (size_t)M_ROWS * E_DIM * 4;     // 50.3 MB
    float*  q    = (float*)ws;                  ws += (size_t)M_ROWS * NQ * 4;        // 0.5 MB
    ushort* w2T  = (ushort*)ws;                 ws += (size_t)FFN_DIM * E_DIM * 2;    // 4.7 MB
    ushort* h    = (ushort*)ws;                 ws += (size_t)M_ROWS * FFN_DIM * 2;   // 100.7 MB

    // 1. A1 = bf16(cos(x + rx))
    k_prep_a1<<<(M_ROWS * E_DIM) / (256 * 4), 256, 0, stream>>>(x, rx, a1);
    // 2. WcT[n,k] = bf16(Wc[k,n]);  W2T[n,k] = bf16(W2[k,n])
    k_transpose_bf<<<dim3(E_DIM / 32, E_DIM / 32), 256, 0, stream>>>(Wc, wcT, E_DIM, E_DIM);
    k_transpose_bf<<<dim3(E_DIM / 32, FFN_DIM / 32), 256, 0, stream>>>(W2, w2T, FFN_DIM, E_DIM);
    // 3. attn = A1 @ Wc + bc
    k_gemm_bt<<<dim3(M_ROWS / 128, E_DIM / 128), 256, 0, stream>>>(a1, wcT, bc, attn, M_ROWS, E_DIM, E_DIM);
    // 4. x1 = LN(x + attn); q = cos(x1[:, :8]) * cos(ry)
    k_ln<<<M_ROWS, 256, 0, stream>>>(x, attn, g1, be1, x1, q, ry, 1);
    // 5. h = relu(q @ W1 + b1)  (bf16)
    k_ffn1<<<M_ROWS / 32, 256, 0, stream>>>(q, W1, b1, h);
    // 6. ffn = h @ W2 + b2  (reuse attn buffer)
    k_gemm_bt<<<dim3(M_ROWS / 128, E_DIM / 128), 256, 0, stream>>>(h, w2T, b2, attn, M_ROWS, E_DIM, FFN_DIM);
    // 7. out = LN(x1 + ffn)
    k_ln<<<M_ROWS, 256, 0, stream>>>(x1, attn, g2, be2, out, nullptr, nullptr, 0);
}